// Round 1
// 300.469 us; speedup vs baseline: 1.0058x; 1.0058x over previous
//
#include <hip/hip_runtime.h>
#include <hip/hip_bf16.h>
#include <stdint.h>

#define MDIM 4096
#define NDIM 4096
#define KDIM 4096
#define NT   (KDIM / 64)   // 64 K-tiles of depth 64

typedef __attribute__((ext_vector_type(8))) short bf16x8;      // MFMA A/B frag (4 VGPRs)
typedef __attribute__((ext_vector_type(4))) float floatx4;     // MFMA C/D frag
typedef __attribute__((ext_vector_type(8))) unsigned short ushort8_t;

// fp32 -> bf16 round-to-nearest-even
__device__ __forceinline__ unsigned short f2bf(float f) {
  union { float f; uint32_t u; } v; v.f = f;
  uint32_t u = v.u;
  u += 0x7FFFu + ((u >> 16) & 1u);
  return (unsigned short)(u >> 16);
}

// async global->LDS, 16B/lane. LDS dest = wave-uniform base + lane*16 (m104/m108).
__device__ __forceinline__ void async_copy16(unsigned short* lds, const unsigned short* g) {
  __builtin_amdgcn_global_load_lds((const __attribute__((address_space(1))) void*)g,
                                   (__attribute__((address_space(3))) void*)lds,
                                   16, 0, 0);
}

// ---------------- fp32 -> bf16 conversion into workspace ----------------
__global__ __launch_bounds__(256) void convert_bf16(const float* __restrict__ x,
                                                    const float* __restrict__ w,
                                                    unsigned short* __restrict__ xb,
                                                    unsigned short* __restrict__ wb) {
  const int64_t off = ((int64_t)blockIdx.x * 256 + threadIdx.x) * 8;
  float4 v0 = *(const float4*)(x + off);
  float4 v1 = *(const float4*)(x + off + 4);
  float4 u0 = *(const float4*)(w + off);
  float4 u1 = *(const float4*)(w + off + 4);
  ushort8_t a = {f2bf(v0.x), f2bf(v0.y), f2bf(v0.z), f2bf(v0.w),
                 f2bf(v1.x), f2bf(v1.y), f2bf(v1.z), f2bf(v1.w)};
  ushort8_t b = {f2bf(u0.x), f2bf(u0.y), f2bf(u0.z), f2bf(u0.w),
                 f2bf(u1.x), f2bf(u1.y), f2bf(u1.z), f2bf(u1.w)};
  *(ushort8_t*)(xb + off) = a;
  *(ushort8_t*)(wb + off) = b;
}

// ---------------- 256x256 8-phase bf16 MFMA GEMM (T2+T3+T4+T5) ----------------
// C[m,n] = sum_k A[m,k]*B[n,k] + bias[n]; A,B bf16 row-major K-contiguous.
//
// LDS per buffer (64 KiB): A as [mh][wm][64][64] (two 16KiB half-units by m-half),
//                          B as [nh][wn][32][64] (two 16KiB half-units by n-half).
// XOR chunk swizzle (proven 0-conflict in prior kernel): 16B chunk slot s of row r
// holds global chunk s ^ (r&7); applied on the GLOBAL source address (gload_lds
// dest must stay linear), undone in the ds_read index.
//
// Phase schedule per K-tile t (buf b = t&1), quadrants (mh,nh):
//   q0=(0,0): stage buf[b^1].A_mh0 <- tile t+1   (region last read (t-1,q3))
//   q1=(1,0): stage buf[b^1].B_nh1 <- tile t+1   (last read (t-1,q3)); vmcnt(6)
//   q2=(1,1): stage buf[b  ].B_nh0 <- tile t+2   (last read (t,q1))
//   q3=(0,1): stage buf[b  ].A_mh1 <- tile t+2   (last read (t,q2));   vmcnt(6)
// Every staged half-unit is confirmed by a vmcnt(6)+barrier before its first read
// (3 half-units = 6 loads stay in flight; never drained to 0 in the main loop).
__global__ __launch_bounds__(512, 2) void gemm_bf16(const unsigned short* __restrict__ A,
                                                    const unsigned short* __restrict__ B,
                                                    const float* __restrict__ bias,
                                                    float* __restrict__ C) {
  __shared__ __align__(16) unsigned short S[2][32768];  // 128 KiB
  const int tid = threadIdx.x;
  const int bm = blockIdx.y, bn = blockIdx.x;
  const int lane = tid & 63;
  const int wave = tid >> 6;                 // 8 waves
  const int quad = lane >> 4, r16 = lane & 15;
  const int wm = wave >> 2, wn = wave & 3;   // 2x4 wave grid; wave tile 128x64

  // staging constants (512 threads, 16B each; one issue = 8KB = 64 rows)
  const int rowa = tid >> 3;                 // 0..63
  const int slot = tid & 7;
  const int ch = slot ^ (rowa & 7);          // swizzled 16B chunk fetched
  const unsigned short* gA0 = A + (int64_t)(bm * 256 + rowa) * KDIM + ch * 8;
  const int growb = (rowa >> 5) * 64 + (rowa & 31);          // B row for p=0 (p=1: +128)
  const unsigned short* gB0 = B + (int64_t)(bn * 256 + growb) * KDIM + ch * 8;

  // ds_read constants (shorts)
  const int offA = wm * 4096 + r16 * 64;
  const int offB = 16384 + wn * 2048 + r16 * 64;
  const int sw0 = (quad ^ (r16 & 7)) * 8;    // k-step h=0 chunk offset
  const int sw1 = sw0 ^ 32;                  // k-step h=1 (chunk ^ 4)

  floatx4 acc[8][4] = {};

#define STAGE_A(BUF, MH, TT) do { \
    unsigned short* d_ = &S[BUF][(MH) * 8192 + tid * 8]; \
    const unsigned short* s_ = gA0 + (int64_t)((MH) * 64) * KDIM + (TT) * 64; \
    async_copy16(d_, s_); \
    async_copy16(d_ + 4096, s_ + (int64_t)128 * KDIM); \
  } while (0)

#define STAGE_B(BUF, NH, TT) do { \
    unsigned short* d_ = &S[BUF][16384 + (NH) * 8192 + tid * 8]; \
    const unsigned short* s_ = gB0 + (int64_t)((NH) * 32) * KDIM + (TT) * 64; \
    async_copy16(d_, s_); \
    async_copy16(d_ + 4096, s_ + (int64_t)128 * KDIM); \
  } while (0)

#define PHASE(BUF, MH, NH, STAGE_STMT, DO_VM) do { \
    const unsigned short* Sb_ = &S[BUF][0]; \
    bf16x8 av_[4][2], bv_[2][2]; \
    _Pragma("unroll") \
    for (int i = 0; i < 4; ++i) { \
      av_[i][0] = *(const bf16x8*)(Sb_ + (MH) * 8192 + offA + i * 1024 + sw0); \
      av_[i][1] = *(const bf16x8*)(Sb_ + (MH) * 8192 + offA + i * 1024 + sw1); \
    } \
    _Pragma("unroll") \
    for (int j = 0; j < 2; ++j) { \
      bv_[j][0] = *(const bf16x8*)(Sb_ + (NH) * 8192 + offB + j * 1024 + sw0); \
      bv_[j][1] = *(const bf16x8*)(Sb_ + (NH) * 8192 + offB + j * 1024 + sw1); \
    } \
    STAGE_STMT; \
    __builtin_amdgcn_s_barrier(); \
    asm volatile("s_waitcnt lgkmcnt(0)" ::: "memory"); \
    __builtin_amdgcn_sched_barrier(0); \
    __builtin_amdgcn_s_setprio(1); \
    _Pragma("unroll") \
    for (int h = 0; h < 2; ++h) \
      _Pragma("unroll") \
      for (int i = 0; i < 4; ++i) \
        _Pragma("unroll") \
        for (int j = 0; j < 2; ++j) \
          acc[(MH) * 4 + i][(NH) * 2 + j] = __builtin_amdgcn_mfma_f32_16x16x32_bf16( \
              av_[i][h], bv_[j][h], acc[(MH) * 4 + i][(NH) * 2 + j], 0, 0, 0); \
    __builtin_amdgcn_s_setprio(0); \
    if (DO_VM) asm volatile("s_waitcnt vmcnt(6)" ::: "memory"); \
    __builtin_amdgcn_s_barrier(); \
  } while (0)

  // prologue: tile0 fully (buf0) + tile1's B_nh0, A_mh1 (buf1) = 12 loads;
  // vmcnt(4) confirms tile0's 8, leaving 2 half-units in flight.
  STAGE_A(0, 0, 0);
  STAGE_A(0, 1, 0);
  STAGE_B(0, 0, 0);
  STAGE_B(0, 1, 0);
  STAGE_B(1, 0, 1);
  STAGE_A(1, 1, 1);
  asm volatile("s_waitcnt vmcnt(4)" ::: "memory");
  __builtin_amdgcn_s_barrier();

  for (int it = 0; it < NT / 2; ++it) {
    const int u = it * 2;
    const int t1 = u + 1;
    const int t2 = (u + 2) & (NT - 1);   // wrapped at tail: harmless re-stage, never read
    const int t3 = (u + 3) & (NT - 1);
    // tile u (buf0)
    PHASE(0, 0, 0, STAGE_A(1, 0, t1), 0);
    PHASE(0, 1, 0, STAGE_B(1, 1, t1), 1);
    PHASE(0, 1, 1, STAGE_B(0, 0, t2), 0);
    PHASE(0, 0, 1, STAGE_A(0, 1, t2), 1);
    // tile u+1 (buf1)
    PHASE(1, 0, 0, STAGE_A(0, 0, t2), 0);
    PHASE(1, 1, 0, STAGE_B(0, 1, t2), 1);
    PHASE(1, 1, 1, STAGE_B(1, 0, t3), 0);
    PHASE(1, 0, 1, STAGE_A(1, 1, t3), 1);
  }
  asm volatile("s_waitcnt vmcnt(0)" ::: "memory");

#undef PHASE
#undef STAGE_A
#undef STAGE_B

  // epilogue: C/D layout col = lane&15, row = quad*4 + r (m89-verified)
  const int col0 = bn * 256 + wn * 64 + r16;
  const int row0 = bm * 256 + wm * 128 + quad * 4;
#pragma unroll
  for (int nj = 0; nj < 4; ++nj) {
    const float bvv = bias[col0 + nj * 16];
#pragma unroll
    for (int mi = 0; mi < 8; ++mi) {
      float* cp = C + (int64_t)(row0 + mi * 16) * NDIM + col0 + nj * 16;
#pragma unroll
      for (int r = 0; r < 4; ++r)
        cp[(int64_t)r * NDIM] = acc[mi][nj][r] + bvv;
    }
  }
}

// ---------------- fallback: fp32 inputs, convert in staging (no workspace) ----------------
#define BM 128
#define BN 128
#define FBK 32
__global__ __launch_bounds__(256) void gemm_f32in(const float* __restrict__ A,
                                                  const float* __restrict__ W,
                                                  const float* __restrict__ bias,
                                                  float* __restrict__ C) {
  __shared__ __align__(16) unsigned short As[BM * FBK];
  __shared__ __align__(16) unsigned short Bs[BN * FBK];
  const int tid = threadIdx.x;
  const int bm = blockIdx.y, bn = blockIdx.x;
  const int lane = tid & 63, wave = tid >> 6;
  const int quad = lane >> 4, r16 = lane & 15;
  const int wm = (wave >> 1) * 64, wn = (wave & 1) * 64;

  const int srow = tid >> 1;
  const int scol = (tid & 1) * 16;
  const float* ag = A + (int64_t)(bm * BM + srow) * KDIM + scol;
  const float* bg = W + (int64_t)(bn * BN + srow) * KDIM + scol;
  unsigned short* al = As + srow * FBK + scol;
  unsigned short* bl = Bs + srow * FBK + scol;

  floatx4 acc[4][4] = {};
  for (int k0 = 0; k0 < KDIM; k0 += FBK) {
    float4 a0 = *(const float4*)(ag + k0);
    float4 a1 = *(const float4*)(ag + k0 + 4);
    float4 a2 = *(const float4*)(ag + k0 + 8);
    float4 a3 = *(const float4*)(ag + k0 + 12);
    float4 b0 = *(const float4*)(bg + k0);
    float4 b1 = *(const float4*)(bg + k0 + 4);
    float4 b2 = *(const float4*)(bg + k0 + 8);
    float4 b3 = *(const float4*)(bg + k0 + 12);
    ushort8_t pa0 = {f2bf(a0.x), f2bf(a0.y), f2bf(a0.z), f2bf(a0.w),
                     f2bf(a1.x), f2bf(a1.y), f2bf(a1.z), f2bf(a1.w)};
    ushort8_t pa1 = {f2bf(a2.x), f2bf(a2.y), f2bf(a2.z), f2bf(a2.w),
                     f2bf(a3.x), f2bf(a3.y), f2bf(a3.z), f2bf(a3.w)};
    ushort8_t pb0 = {f2bf(b0.x), f2bf(b0.y), f2bf(b0.z), f2bf(b0.w),
                     f2bf(b1.x), f2bf(b1.y), f2bf(b1.z), f2bf(b1.w)};
    ushort8_t pb1 = {f2bf(b2.x), f2bf(b2.y), f2bf(b2.z), f2bf(b2.w),
                     f2bf(b3.x), f2bf(b3.y), f2bf(b3.z), f2bf(b3.w)};
    *(ushort8_t*)al = pa0;
    *(ushort8_t*)(al + 8) = pa1;
    *(ushort8_t*)bl = pb0;
    *(ushort8_t*)(bl + 8) = pb1;
    __syncthreads();

    bf16x8 a[4], b[4];
#pragma unroll
    for (int i = 0; i < 4; ++i)
      a[i] = *(const bf16x8*)(As + (wm + i * 16 + r16) * FBK + quad * 8);
#pragma unroll
    for (int i = 0; i < 4; ++i)
      b[i] = *(const bf16x8*)(Bs + (wn + i * 16 + r16) * FBK + quad * 8);
#pragma unroll
    for (int i = 0; i < 4; ++i)
#pragma unroll
      for (int j = 0; j < 4; ++j)
        acc[i][j] = __builtin_amdgcn_mfma_f32_16x16x32_bf16(a[i], b[j], acc[i][j], 0, 0, 0);
    __syncthreads();
  }

  const int col0 = bn * BN + wn + r16;
  const int row0 = bm * BM + wm + quad * 4;
#pragma unroll
  for (int j = 0; j < 4; ++j) {
    const float bv = bias[col0 + j * 16];
#pragma unroll
    for (int i = 0; i < 4; ++i) {
      float* cp = C + (int64_t)(row0 + i * 16) * NDIM + col0 + j * 16;
#pragma unroll
      for (int r = 0; r < 4; ++r)
        cp[(int64_t)r * NDIM] = acc[i][j][r] + bv;
    }
  }
}

extern "C" void kernel_launch(void* const* d_in, const int* in_sizes, int n_in,
                              void* d_out, int out_size, void* d_ws, size_t ws_size,
                              hipStream_t stream) {
  const float* x    = (const float*)d_in[0];   // [4096, 4096]
  const float* w    = (const float*)d_in[1];   // [4096, 4096]
  const float* bias = (const float*)d_in[2];   // [4096]
  float* out = (float*)d_out;

  const size_t need = (size_t)2 * MDIM * KDIM * sizeof(unsigned short);  // 64 MB
  if (ws_size >= need) {
    unsigned short* xb = (unsigned short*)d_ws;
    unsigned short* wb = xb + (size_t)MDIM * KDIM;
    convert_bf16<<<8192, 256, 0, stream>>>(x, w, xb, wb);
    dim3 grid(NDIM / 256, MDIM / 256);  // 16 x 16 = 256 blocks, 1/CU
    gemm_bf16<<<grid, 512, 0, stream>>>(xb, wb, bias, out);
  } else {
    dim3 grid(NDIM / BN, MDIM / BM);
    gemm_f32in<<<grid, 256, 0, stream>>>(x, w, bias, out);
  }
}

// Round 2
// 283.378 us; speedup vs baseline: 1.0665x; 1.0603x over previous
//
#include <hip/hip_runtime.h>
#include <hip/hip_bf16.h>
#include <stdint.h>

#define MDIM 4096
#define NDIM 4096
#define KDIM 4096
#define NT   (KDIM / 64)   // 64 K-tiles of depth 64

typedef __attribute__((ext_vector_type(8))) short bf16x8;      // MFMA A/B frag (4 VGPRs)
typedef __attribute__((ext_vector_type(4))) float floatx4;     // MFMA C/D frag
typedef __attribute__((ext_vector_type(8))) unsigned short ushort8_t;
typedef __attribute__((ext_vector_type(4))) unsigned short ushort4_t;

// fp32 -> bf16 round-to-nearest-even
__device__ __forceinline__ unsigned short f2bf(float f) {
  union { float f; uint32_t u; } v; v.f = f;
  uint32_t u = v.u;
  u += 0x7FFFu + ((u >> 16) & 1u);
  return (unsigned short)(u >> 16);
}

// async global->LDS, 16B/lane. LDS dest = wave-uniform base + lane*16 (m104/m108).
__device__ __forceinline__ void async_copy16(unsigned short* lds, const unsigned short* g) {
  __builtin_amdgcn_global_load_lds((const __attribute__((address_space(1))) void*)g,
                                   (__attribute__((address_space(3))) void*)lds,
                                   16, 0, 0);
}

// ---------------- fp32 -> bf16 conversion into workspace ----------------
// v2: 4 floats/thread. Loads are lane-contiguous 16B (one 64B line per 4 lanes,
// touched by exactly one instruction), stores lane-contiguous 8B. The old
// 8-floats/thread version had lane-stride-32B float4 pairs (every line hit by
// two instructions -> 2x L2 requests) and ran at only ~1.35 TB/s.
__global__ __launch_bounds__(256) void convert_bf16(const float* __restrict__ x,
                                                    const float* __restrict__ w,
                                                    unsigned short* __restrict__ xb,
                                                    unsigned short* __restrict__ wb) {
  const int64_t off = ((int64_t)blockIdx.x * 256 + threadIdx.x) * 4;
  float4 v = *(const float4*)(x + off);
  float4 u = *(const float4*)(w + off);
  ushort4_t a = {f2bf(v.x), f2bf(v.y), f2bf(v.z), f2bf(v.w)};
  ushort4_t b = {f2bf(u.x), f2bf(u.y), f2bf(u.z), f2bf(u.w)};
  *(ushort4_t*)(xb + off) = a;
  *(ushort4_t*)(wb + off) = b;
}

// ---------------- 256x256 8-phase bf16 MFMA GEMM, Gray-code operand reuse ----------------
// C[m,n] = sum_k A[m,k]*B[n,k] + bias[n]; A,B bf16 row-major K-contiguous.
//
// Phase order per K-tile: (MH,NH) = (0,0) -> (0,1) -> (1,1) -> (1,0).
// Consecutive phases share one operand, which stays in registers:
//   P0: read A0->av, B0->bv (12 ds_read_b128)   P1: read B1->bv (4)
//   P2: read A1->av (8)                          P3: re-read B0->bv (4)
// 28 reads/wave/K-tile (was 48) -> LDS read traffic 224KB/CU/K-tile (was 384KB).
//
// Staging (2 x global_load_lds per half-unit, issue order matters for vmcnt):
//   tile t P0: B1(t+1)->buf^1, B0(t+1)->buf^1
//   tile t P1: A0(t+2)->buf,   A1(t+1)->buf^1
// Waits: vmcnt(6) at P1, vmcnt(4) at P3. Derived confirm schedule:
//   B1(t+1),A1(t),A0(t+1) confirmed at (t,P1); B0(t+1) at (t,P3) -- each before
//   its first read; every stage target is barrier-separated from the prior
//   reads of its region (reads drain at each wave's lgkmcnt(0) before the
//   closing barrier of their phase).
__global__ __launch_bounds__(512, 2) void gemm_bf16(const unsigned short* __restrict__ A,
                                                    const unsigned short* __restrict__ B,
                                                    const float* __restrict__ bias,
                                                    float* __restrict__ C) {
  __shared__ __align__(16) unsigned short S[2][32768];  // 128 KiB
  const int tid = threadIdx.x;
  const int bm = blockIdx.y, bn = blockIdx.x;
  const int lane = tid & 63;
  const int wave = tid >> 6;                 // 8 waves
  const int quad = lane >> 4, r16 = lane & 15;
  const int wm = wave >> 2, wn = wave & 3;   // 2x4 wave grid; wave tile 128x64

  // staging constants (512 threads, 16B each; one issue = 8KB = 64 rows)
  const int rowa = tid >> 3;                 // 0..63
  const int slot = tid & 7;
  const int ch = slot ^ (rowa & 7);          // swizzled 16B chunk fetched
  const unsigned short* gA0 = A + (int64_t)(bm * 256 + rowa) * KDIM + ch * 8;
  const int growb = (rowa >> 5) * 64 + (rowa & 31);
  const unsigned short* gB0 = B + (int64_t)(bn * 256 + growb) * KDIM + ch * 8;

  // ds_read constants (shorts)
  const int offA = wm * 4096 + r16 * 64;
  const int offB = 16384 + wn * 2048 + r16 * 64;
  const int sw0 = (quad ^ (r16 & 7)) * 8;    // k-step h=0 chunk offset
  const int sw1 = sw0 ^ 32;                  // k-step h=1 (chunk ^ 4)

  floatx4 acc[8][4] = {};
  bf16x8 av[4][2], bv[2][2];                 // persistent operand fragments

#define STAGE_A(BUF, MH, TT) do { \
    unsigned short* d_ = &S[BUF][(MH) * 8192 + tid * 8]; \
    const unsigned short* s_ = gA0 + (int64_t)((MH) * 64) * KDIM + (TT) * 64; \
    async_copy16(d_, s_); \
    async_copy16(d_ + 4096, s_ + (int64_t)128 * KDIM); \
  } while (0)

#define STAGE_B(BUF, NH, TT) do { \
    unsigned short* d_ = &S[BUF][16384 + (NH) * 8192 + tid * 8]; \
    const unsigned short* s_ = gB0 + (int64_t)((NH) * 32) * KDIM + (TT) * 64; \
    async_copy16(d_, s_); \
    async_copy16(d_ + 4096, s_ + (int64_t)128 * KDIM); \
  } while (0)

  // RA/RB: whether this phase refreshes av / bv. DO_VM: 0 (none) or vmcnt literal.
#define PHASE(BUF, MH, NH, RA, RB, STAGE_STMT, DO_VM) do { \
    const unsigned short* Sb_ = &S[BUF][0]; \
    if (RA) { \
      _Pragma("unroll") \
      for (int i = 0; i < 4; ++i) { \
        av[i][0] = *(const bf16x8*)(Sb_ + (MH) * 8192 + offA + i * 1024 + sw0); \
        av[i][1] = *(const bf16x8*)(Sb_ + (MH) * 8192 + offA + i * 1024 + sw1); \
      } \
    } \
    if (RB) { \
      _Pragma("unroll") \
      for (int j = 0; j < 2; ++j) { \
        bv[j][0] = *(const bf16x8*)(Sb_ + (NH) * 8192 + offB + j * 1024 + sw0); \
        bv[j][1] = *(const bf16x8*)(Sb_ + (NH) * 8192 + offB + j * 1024 + sw1); \
      } \
    } \
    STAGE_STMT; \
    __builtin_amdgcn_s_barrier(); \
    asm volatile("s_waitcnt lgkmcnt(0)" ::: "memory"); \
    __builtin_amdgcn_sched_barrier(0); \
    __builtin_amdgcn_s_setprio(1); \
    _Pragma("unroll") \
    for (int h = 0; h < 2; ++h) \
      _Pragma("unroll") \
      for (int i = 0; i < 4; ++i) \
        _Pragma("unroll") \
        for (int j = 0; j < 2; ++j) \
          acc[(MH) * 4 + i][(NH) * 2 + j] = __builtin_amdgcn_mfma_f32_16x16x32_bf16( \
              av[i][h], bv[j][h], acc[(MH) * 4 + i][(NH) * 2 + j], 0, 0, 0); \
    __builtin_amdgcn_s_setprio(0); \
    if (DO_VM) { asm volatile("s_waitcnt vmcnt(%0)" :: "i"(DO_VM) : "memory"); } \
    __builtin_amdgcn_s_barrier(); \
  } while (0)

  // prologue: tile0 fully (8 loads, confirmed) + A0(1)->buf1 (left in flight).
  STAGE_A(0, 0, 0);
  STAGE_B(0, 0, 0);
  STAGE_B(0, 1, 0);
  STAGE_A(0, 1, 0);
  STAGE_A(1, 0, 1);
  asm volatile("s_waitcnt vmcnt(2)" ::: "memory");
  __builtin_amdgcn_s_barrier();

  for (int it = 0; it < NT / 2; ++it) {
    const int u = it * 2;
    const int t1 = u + 1;
    const int t2 = (u + 2) & (NT - 1);   // wrapped at tail: staged but never read
    const int t3 = (u + 3) & (NT - 1);
    // tile u (buf0)
    PHASE(0, 0, 0, 1, 1, { STAGE_B(1, 1, t1); STAGE_B(1, 0, t1); }, 0);
    PHASE(0, 0, 1, 0, 1, { STAGE_A(0, 0, t2); STAGE_A(1, 1, t1); }, 6);
    PHASE(0, 1, 1, 1, 0, {}, 0);
    PHASE(0, 1, 0, 0, 1, {}, 4);
    // tile u+1 (buf1)
    PHASE(1, 0, 0, 1, 1, { STAGE_B(0, 1, t2); STAGE_B(0, 0, t2); }, 0);
    PHASE(1, 0, 1, 0, 1, { STAGE_A(1, 0, t3); STAGE_A(0, 1, t2); }, 6);
    PHASE(1, 1, 1, 1, 0, {}, 0);
    PHASE(1, 1, 0, 0, 1, {}, 4);
  }
  asm volatile("s_waitcnt vmcnt(0)" ::: "memory");

#undef PHASE
#undef STAGE_A
#undef STAGE_B

  // epilogue: C/D layout col = lane&15, row = quad*4 + r (m89-verified)
  const int col0 = bn * 256 + wn * 64 + r16;
  const int row0 = bm * 256 + wm * 128 + quad * 4;
#pragma unroll
  for (int nj = 0; nj < 4; ++nj) {
    const float bvv = bias[col0 + nj * 16];
#pragma unroll
    for (int mi = 0; mi < 8; ++mi) {
      float* cp = C + (int64_t)(row0 + mi * 16) * NDIM + col0 + nj * 16;
#pragma unroll
      for (int r = 0; r < 4; ++r)
        cp[(int64_t)r * NDIM] = acc[mi][nj][r] + bvv;
    }
  }
}

// ---------------- fallback: fp32 inputs, convert in staging (no workspace) ----------------
#define BM 128
#define BN 128
#define FBK 32
__global__ __launch_bounds__(256) void gemm_f32in(const float* __restrict__ A,
                                                  const float* __restrict__ W,
                                                  const float* __restrict__ bias,
                                                  float* __restrict__ C) {
  __shared__ __align__(16) unsigned short As[BM * FBK];
  __shared__ __align__(16) unsigned short Bs[BN * FBK];
  const int tid = threadIdx.x;
  const int bm = blockIdx.y, bn = blockIdx.x;
  const int lane = tid & 63, wave = tid >> 6;
  const int quad = lane >> 4, r16 = lane & 15;
  const int wm = (wave >> 1) * 64, wn = (wave & 1) * 64;

  const int srow = tid >> 1;
  const int scol = (tid & 1) * 16;
  const float* ag = A + (int64_t)(bm * BM + srow) * KDIM + scol;
  const float* bg = W + (int64_t)(bn * BN + srow) * KDIM + scol;
  unsigned short* al = As + srow * FBK + scol;
  unsigned short* bl = Bs + srow * FBK + scol;

  floatx4 acc[4][4] = {};
  for (int k0 = 0; k0 < KDIM; k0 += FBK) {
    float4 a0 = *(const float4*)(ag + k0);
    float4 a1 = *(const float4*)(ag + k0 + 4);
    float4 a2 = *(const float4*)(ag + k0 + 8);
    float4 a3 = *(const float4*)(ag + k0 + 12);
    float4 b0 = *(const float4*)(bg + k0);
    float4 b1 = *(const float4*)(bg + k0 + 4);
    float4 b2 = *(const float4*)(bg + k0 + 8);
    float4 b3 = *(const float4*)(bg + k0 + 12);
    ushort8_t pa0 = {f2bf(a0.x), f2bf(a0.y), f2bf(a0.z), f2bf(a0.w),
                     f2bf(a1.x), f2bf(a1.y), f2bf(a1.z), f2bf(a1.w)};
    ushort8_t pa1 = {f2bf(a2.x), f2bf(a2.y), f2bf(a2.z), f2bf(a2.w),
                     f2bf(a3.x), f2bf(a3.y), f2bf(a3.z), f2bf(a3.w)};
    ushort8_t pb0 = {f2bf(b0.x), f2bf(b0.y), f2bf(b0.z), f2bf(b0.w),
                     f2bf(b1.x), f2bf(b1.y), f2bf(b1.z), f2bf(b1.w)};
    ushort8_t pb1 = {f2bf(b2.x), f2bf(b2.y), f2bf(b2.z), f2bf(b2.w),
                     f2bf(b3.x), f2bf(b3.y), f2bf(b3.z), f2bf(b3.w)};
    *(ushort8_t*)al = pa0;
    *(ushort8_t*)(al + 8) = pa1;
    *(ushort8_t*)bl = pb0;
    *(ushort8_t*)(bl + 8) = pb1;
    __syncthreads();

    bf16x8 a[4], b[4];
#pragma unroll
    for (int i = 0; i < 4; ++i)
      a[i] = *(const bf16x8*)(As + (wm + i * 16 + r16) * FBK + quad * 8);
#pragma unroll
    for (int i = 0; i < 4; ++i)
      b[i] = *(const bf16x8*)(Bs + (wn + i * 16 + r16) * FBK + quad * 8);
#pragma unroll
    for (int i = 0; i < 4; ++i)
#pragma unroll
      for (int j = 0; j < 4; ++j)
        acc[i][j] = __builtin_amdgcn_mfma_f32_16x16x32_bf16(a[i], b[j], acc[i][j], 0, 0, 0);
    __syncthreads();
  }

  const int col0 = bn * BN + wn + r16;
  const int row0 = bm * BM + wm + quad * 4;
#pragma unroll
  for (int j = 0; j < 4; ++j) {
    const float bv = bias[col0 + j * 16];
#pragma unroll
    for (int i = 0; i < 4; ++i) {
      float* cp = C + (int64_t)(row0 + i * 16) * NDIM + col0 + j * 16;
#pragma unroll
      for (int r = 0; r < 4; ++r)
        cp[(int64_t)r * NDIM] = acc[i][j][r] + bv;
    }
  }
}

extern "C" void kernel_launch(void* const* d_in, const int* in_sizes, int n_in,
                              void* d_out, int out_size, void* d_ws, size_t ws_size,
                              hipStream_t stream) {
  const float* x    = (const float*)d_in[0];   // [4096, 4096]
  const float* w    = (const float*)d_in[1];   // [4096, 4096]
  const float* bias = (const float*)d_in[2];   // [4096]
  float* out = (float*)d_out;

  const size_t need = (size_t)2 * MDIM * KDIM * sizeof(unsigned short);  // 64 MB
  if (ws_size >= need) {
    unsigned short* xb = (unsigned short*)d_ws;
    unsigned short* wb = xb + (size_t)MDIM * KDIM;
    convert_bf16<<<16384, 256, 0, stream>>>(x, w, xb, wb);
    dim3 grid(NDIM / 256, MDIM / 256);  // 16 x 16 = 256 blocks, 1/CU
    gemm_bf16<<<grid, 512, 0, stream>>>(xb, wb, bias, out);
  } else {
    dim3 grid(NDIM / BN, MDIM / BM);
    gemm_f32in<<<grid, 256, 0, stream>>>(x, w, bias, out);
  }
}

// Round 3
// 281.547 us; speedup vs baseline: 1.0734x; 1.0065x over previous
//
#include <hip/hip_runtime.h>
#include <hip/hip_bf16.h>
#include <stdint.h>

#define MDIM 4096
#define NDIM 4096
#define KDIM 4096
#define NT   (KDIM / 64)   // 64 K-tiles of depth 64

typedef __attribute__((ext_vector_type(8))) short bf16x8;      // MFMA A/B frag (4 VGPRs)
typedef __attribute__((ext_vector_type(4))) float floatx4;     // MFMA C/D frag
typedef __attribute__((ext_vector_type(8))) unsigned short ushort8_t;
typedef __attribute__((ext_vector_type(4))) unsigned short ushort4_t;

// fp32 -> bf16 round-to-nearest-even
__device__ __forceinline__ unsigned short f2bf(float f) {
  union { float f; uint32_t u; } v; v.f = f;
  uint32_t u = v.u;
  u += 0x7FFFu + ((u >> 16) & 1u);
  return (unsigned short)(u >> 16);
}

// async global->LDS, 16B/lane. LDS dest = wave-uniform base + lane*16 (m104/m108).
__device__ __forceinline__ void async_copy16(unsigned short* lds, const unsigned short* g) {
  __builtin_amdgcn_global_load_lds((const __attribute__((address_space(1))) void*)g,
                                   (__attribute__((address_space(3))) void*)lds,
                                   16, 0, 0);
}

// ---------------- fp32 -> bf16 conversion into workspace ----------------
// v3: single-stream grid-stride. Blocks [0,2048) convert x, [2048,4096) convert w;
// each block owns ONE read stream + ONE write stream (v2 interleaved 4 streams
// per block and ran ~1.3 TB/s). float4 in (16B/lane), ushort4 out (8B/lane).
__global__ __launch_bounds__(256) void convert_bf16(const float* __restrict__ x,
                                                    const float* __restrict__ w,
                                                    unsigned short* __restrict__ xb,
                                                    unsigned short* __restrict__ wb) {
  const int half = gridDim.x >> 1;
  const float* src;
  unsigned short* dst;
  int b = blockIdx.x;
  if (b < half) { src = x; dst = xb; } else { src = w; dst = wb; b -= half; }
  const int64_t total  = (int64_t)MDIM * KDIM;            // 16.78M elements
  const int64_t stride = (int64_t)half * 256 * 4;         // elements per sweep
  for (int64_t off = ((int64_t)b * 256 + threadIdx.x) * 4; off < total; off += stride) {
    float4 v = *(const float4*)(src + off);
    ushort4_t a = {f2bf(v.x), f2bf(v.y), f2bf(v.z), f2bf(v.w)};
    *(ushort4_t*)(dst + off) = a;
  }
}

// ---------------- 256x256 8-phase bf16 MFMA GEMM ----------------
// C[m,n] = sum_k A[m,k]*B[n,k] + bias[n]; A,B bf16 row-major K-contiguous.
//
// v3 schedule. Phase order (MH,NH): (0,0) -> (0,1) -> (1,1) -> (1,0).
// Register retention: av holds the active A-half; bv0 holds B0 for the WHOLE
// tile (used P0 and P3), bv1 holds B1 (P1,P2). ds_reads/wave/tile = 24
// (12,4,8,0 per phase) -- the minimum (each fragment read exactly once).
//
// Staging: ONE half-unit per phase (2 global_load_lds), targets buf^1:
//   P0: A0(t+1)   P1: B0(t+1)   P2: B1(t+1)   P3: A1(t+1)
// Waits: vmcnt(4) at end of P0, P1, P3 (none at P2). FIFO trace (steady state,
// queue oldest->newest, 2 instr per unit):
//   end P3(t-1): [B1(t), A1(t)]
//   P0(t): read A0,B0(t) (conf @P3(t-1)); +A0(t+1) -> 6; vmcnt4 confirms B1(t)
//   P1(t): read B1(t); +B0(t+1) -> 6; vmcnt4 confirms A1(t)
//   P2(t): read A1(t); +B1(t+1) -> 6; no wait
//   P3(t): no reads;   +A1(t+1) -> 8; vmcnt4 confirms A0(t+1),B0(t+1)
// Every unit is in flight 2-3 phases (~2000+ cyc > HBM ~900) and confirmed
// (vmcnt + barrier) before first read. Stage targets (buf^1) were last read
// one full tile earlier -> >=1 barrier separation (reads drain at each wave's
// lgkmcnt(0) before the phase-closing barrier).
__global__ __launch_bounds__(512, 2) void gemm_bf16(const unsigned short* __restrict__ A,
                                                    const unsigned short* __restrict__ B,
                                                    const float* __restrict__ bias,
                                                    float* __restrict__ C) {
  __shared__ __align__(16) unsigned short S[2][32768];  // 128 KiB
  const int tid = threadIdx.x;
  const int bm = blockIdx.y, bn = blockIdx.x;
  const int lane = tid & 63;
  const int wave = tid >> 6;                 // 8 waves
  const int quad = lane >> 4, r16 = lane & 15;
  const int wm = wave >> 2, wn = wave & 3;   // 2x4 wave grid; wave tile 128x64

  // staging constants (512 threads, 16B each; one issue = 8KB = 64 rows)
  const int rowa = tid >> 3;                 // 0..63
  const int slot = tid & 7;
  const int ch = slot ^ (rowa & 7);          // swizzled 16B chunk fetched
  const unsigned short* gA0 = A + (int64_t)(bm * 256 + rowa) * KDIM + ch * 8;
  const int growb = (rowa >> 5) * 64 + (rowa & 31);
  const unsigned short* gB0 = B + (int64_t)(bn * 256 + growb) * KDIM + ch * 8;

  // ds_read constants (shorts)
  const int offA = wm * 4096 + r16 * 64;
  const int offB = 16384 + wn * 2048 + r16 * 64;
  const int sw0 = (quad ^ (r16 & 7)) * 8;    // k-step h=0 chunk offset
  const int sw1 = sw0 ^ 32;                  // k-step h=1 (chunk ^ 4)

  floatx4 acc[8][4] = {};
  bf16x8 av[4][2];       // active A-half fragments
  bf16x8 bv0[2][2];      // B half 0, live whole tile (P0 & P3)
  bf16x8 bv1[2][2];      // B half 1 (P1 & P2)

#define STAGE_A(BUF, MH, TT) do { \
    unsigned short* d_ = &S[BUF][(MH) * 8192 + tid * 8]; \
    const unsigned short* s_ = gA0 + (int64_t)((MH) * 64) * KDIM + (TT) * 64; \
    async_copy16(d_, s_); \
    async_copy16(d_ + 4096, s_ + (int64_t)128 * KDIM); \
  } while (0)

#define STAGE_B(BUF, NH, TT) do { \
    unsigned short* d_ = &S[BUF][16384 + (NH) * 8192 + tid * 8]; \
    const unsigned short* s_ = gB0 + (int64_t)((NH) * 32) * KDIM + (TT) * 64; \
    async_copy16(d_, s_); \
    async_copy16(d_ + 4096, s_ + (int64_t)128 * KDIM); \
  } while (0)

#define VM4 asm volatile("s_waitcnt vmcnt(4)" ::: "memory")
#define VMNONE (void)0

  // RA: refresh av from half MH. RB: refresh BVARR from half NH.
#define PHASE(BUF, RA, MH, RB, NH, BVARR, MOFF, NOFF, STAGE_STMT, WAIT_STMT) do { \
    const unsigned short* Sb_ = &S[BUF][0]; \
    if (RA) { \
      _Pragma("unroll") \
      for (int i = 0; i < 4; ++i) { \
        av[i][0] = *(const bf16x8*)(Sb_ + (MH) * 8192 + offA + i * 1024 + sw0); \
        av[i][1] = *(const bf16x8*)(Sb_ + (MH) * 8192 + offA + i * 1024 + sw1); \
      } \
    } \
    if (RB) { \
      _Pragma("unroll") \
      for (int j = 0; j < 2; ++j) { \
        BVARR[j][0] = *(const bf16x8*)(Sb_ + (NH) * 8192 + offB + j * 1024 + sw0); \
        BVARR[j][1] = *(const bf16x8*)(Sb_ + (NH) * 8192 + offB + j * 1024 + sw1); \
      } \
    } \
    STAGE_STMT; \
    __builtin_amdgcn_s_barrier(); \
    asm volatile("s_waitcnt lgkmcnt(0)" ::: "memory"); \
    __builtin_amdgcn_sched_barrier(0); \
    __builtin_amdgcn_s_setprio(1); \
    _Pragma("unroll") \
    for (int h = 0; h < 2; ++h) \
      _Pragma("unroll") \
      for (int i = 0; i < 4; ++i) \
        _Pragma("unroll") \
        for (int j = 0; j < 2; ++j) \
          acc[(MOFF) + i][(NOFF) + j] = __builtin_amdgcn_mfma_f32_16x16x32_bf16( \
              av[i][h], BVARR[j][h], acc[(MOFF) + i][(NOFF) + j], 0, 0, 0); \
    __builtin_amdgcn_s_setprio(0); \
    WAIT_STMT; \
    __builtin_amdgcn_s_barrier(); \
  } while (0)

  // prologue: tile 0 fully into buf0, FIFO order A0,B0,B1,A1; confirm A0,B0.
  STAGE_A(0, 0, 0);
  STAGE_B(0, 0, 0);
  STAGE_B(0, 1, 0);
  STAGE_A(0, 1, 0);
  asm volatile("s_waitcnt vmcnt(4)" ::: "memory");
  __builtin_amdgcn_s_barrier();

  for (int it = 0; it < NT / 2; ++it) {
    const int u = it * 2;
    const int t1 = u + 1;
    const int t2 = (u + 2) & (NT - 1);   // wrapped at tail: staged but never read
    // tile u (buf0; stage tile t1 -> buf1)
    PHASE(0, 1, 0, 1, 0, bv0, 0, 0, STAGE_A(1, 0, t1), VM4);
    PHASE(0, 0, 0, 1, 1, bv1, 0, 2, STAGE_B(1, 0, t1), VM4);
    PHASE(0, 1, 1, 0, 0, bv1, 4, 2, STAGE_B(1, 1, t1), VMNONE);
    PHASE(0, 0, 0, 0, 0, bv0, 4, 0, STAGE_A(1, 1, t1), VM4);
    // tile t1 (buf1; stage tile t2 -> buf0)
    PHASE(1, 1, 0, 1, 0, bv0, 0, 0, STAGE_A(0, 0, t2), VM4);
    PHASE(1, 0, 0, 1, 1, bv1, 0, 2, STAGE_B(0, 0, t2), VM4);
    PHASE(1, 1, 1, 0, 0, bv1, 4, 2, STAGE_B(0, 1, t2), VMNONE);
    PHASE(1, 0, 0, 0, 0, bv0, 4, 0, STAGE_A(0, 1, t2), VM4);
  }
  asm volatile("s_waitcnt vmcnt(0)" ::: "memory");

#undef PHASE
#undef VM4
#undef VMNONE
#undef STAGE_A
#undef STAGE_B

  // epilogue: C/D layout col = lane&15, row = quad*4 + r (m89-verified)
  const int col0 = bn * 256 + wn * 64 + r16;
  const int row0 = bm * 256 + wm * 128 + quad * 4;
#pragma unroll
  for (int nj = 0; nj < 4; ++nj) {
    const float bvv = bias[col0 + nj * 16];
#pragma unroll
    for (int mi = 0; mi < 8; ++mi) {
      float* cp = C + (int64_t)(row0 + mi * 16) * NDIM + col0 + nj * 16;
#pragma unroll
      for (int r = 0; r < 4; ++r)
        cp[(int64_t)r * NDIM] = acc[mi][nj][r] + bvv;
    }
  }
}

// ---------------- fallback: fp32 inputs, convert in staging (no workspace) ----------------
#define BM 128
#define BN 128
#define FBK 32
__global__ __launch_bounds__(256) void gemm_f32in(const float* __restrict__ A,
                                                  const float* __restrict__ W,
                                                  const float* __restrict__ bias,
                                                  float* __restrict__ C) {
  __shared__ __align__(16) unsigned short As[BM * FBK];
  __shared__ __align__(16) unsigned short Bs[BN * FBK];
  const int tid = threadIdx.x;
  const int bm = blockIdx.y, bn = blockIdx.x;
  const int lane = tid & 63, wave = tid >> 6;
  const int quad = lane >> 4, r16 = lane & 15;
  const int wm = (wave >> 1) * 64, wn = (wave & 1) * 64;

  const int srow = tid >> 1;
  const int scol = (tid & 1) * 16;
  const float* ag = A + (int64_t)(bm * BM + srow) * KDIM + scol;
  const float* bg = W + (int64_t)(bn * BN + srow) * KDIM + scol;
  unsigned short* al = As + srow * FBK + scol;
  unsigned short* bl = Bs + srow * FBK + scol;

  floatx4 acc[4][4] = {};
  for (int k0 = 0; k0 < KDIM; k0 += FBK) {
    float4 a0 = *(const float4*)(ag + k0);
    float4 a1 = *(const float4*)(ag + k0 + 4);
    float4 a2 = *(const float4*)(ag + k0 + 8);
    float4 a3 = *(const float4*)(ag + k0 + 12);
    float4 b0 = *(const float4*)(bg + k0);
    float4 b1 = *(const float4*)(bg + k0 + 4);
    float4 b2 = *(const float4*)(bg + k0 + 8);
    float4 b3 = *(const float4*)(bg + k0 + 12);
    ushort8_t pa0 = {f2bf(a0.x), f2bf(a0.y), f2bf(a0.z), f2bf(a0.w),
                     f2bf(a1.x), f2bf(a1.y), f2bf(a1.z), f2bf(a1.w)};
    ushort8_t pa1 = {f2bf(a2.x), f2bf(a2.y), f2bf(a2.z), f2bf(a2.w),
                     f2bf(a3.x), f2bf(a3.y), f2bf(a3.z), f2bf(a3.w)};
    ushort8_t pb0 = {f2bf(b0.x), f2bf(b0.y), f2bf(b0.z), f2bf(b0.w),
                     f2bf(b1.x), f2bf(b1.y), f2bf(b1.z), f2bf(b1.w)};
    ushort8_t pb1 = {f2bf(b2.x), f2bf(b2.y), f2bf(b2.z), f2bf(b2.w),
                     f2bf(b3.x), f2bf(b3.y), f2bf(b3.z), f2bf(b3.w)};
    *(ushort8_t*)al = pa0;
    *(ushort8_t*)(al + 8) = pa1;
    *(ushort8_t*)bl = pb0;
    *(ushort8_t*)(bl + 8) = pb1;
    __syncthreads();

    bf16x8 a[4], b[4];
#pragma unroll
    for (int i = 0; i < 4; ++i)
      a[i] = *(const bf16x8*)(As + (wm + i * 16 + r16) * FBK + quad * 8);
#pragma unroll
    for (int i = 0; i < 4; ++i)
      b[i] = *(const bf16x8*)(Bs + (wn + i * 16 + r16) * FBK + quad * 8);
#pragma unroll
    for (int i = 0; i < 4; ++i)
#pragma unroll
      for (int j = 0; j < 4; ++j)
        acc[i][j] = __builtin_amdgcn_mfma_f32_16x16x32_bf16(a[i], b[j], acc[i][j], 0, 0, 0);
    __syncthreads();
  }

  const int col0 = bn * BN + wn + r16;
  const int row0 = bm * BM + wm + quad * 4;
#pragma unroll
  for (int j = 0; j < 4; ++j) {
    const float bv = bias[col0 + j * 16];
#pragma unroll
    for (int i = 0; i < 4; ++i) {
      float* cp = C + (int64_t)(row0 + i * 16) * NDIM + col0 + j * 16;
#pragma unroll
      for (int r = 0; r < 4; ++r)
        cp[(int64_t)r * NDIM] = acc[i][j][r] + bv;
    }
  }
}

extern "C" void kernel_launch(void* const* d_in, const int* in_sizes, int n_in,
                              void* d_out, int out_size, void* d_ws, size_t ws_size,
                              hipStream_t stream) {
  const float* x    = (const float*)d_in[0];   // [4096, 4096]
  const float* w    = (const float*)d_in[1];   // [4096, 4096]
  const float* bias = (const float*)d_in[2];   // [4096]
  float* out = (float*)d_out;

  const size_t need = (size_t)2 * MDIM * KDIM * sizeof(unsigned short);  // 64 MB
  if (ws_size >= need) {
    unsigned short* xb = (unsigned short*)d_ws;
    unsigned short* wb = xb + (size_t)MDIM * KDIM;
    convert_bf16<<<4096, 256, 0, stream>>>(x, w, xb, wb);
    dim3 grid(NDIM / 256, MDIM / 256);  // 16 x 16 = 256 blocks, 1/CU
    gemm_bf16<<<grid, 512, 0, stream>>>(xb, wb, bias, out);
  } else {
    dim3 grid(NDIM / BN, MDIM / BM);
    gemm_f32in<<<grid, 256, 0, stream>>>(x, w, bias, out);
  }
}

// Round 4
// 279.353 us; speedup vs baseline: 1.0819x; 1.0079x over previous
//
#include <hip/hip_runtime.h>
#include <hip/hip_bf16.h>
#include <stdint.h>

#define MDIM 4096
#define NDIM 4096
#define KDIM 4096
#define NT   (KDIM / 64)   // 64 K-tiles of depth 64

typedef __attribute__((ext_vector_type(8))) short bf16x8;      // MFMA A/B frag (4 VGPRs)
typedef __attribute__((ext_vector_type(4))) float floatx4;     // MFMA C/D frag
typedef __attribute__((ext_vector_type(8))) unsigned short ushort8_t;
typedef __attribute__((ext_vector_type(4))) unsigned short ushort4_t;

// fp32 -> bf16 round-to-nearest-even
__device__ __forceinline__ unsigned short f2bf(float f) {
  union { float f; uint32_t u; } v; v.f = f;
  uint32_t u = v.u;
  u += 0x7FFFu + ((u >> 16) & 1u);
  return (unsigned short)(u >> 16);
}

// async global->LDS, 16B/lane. LDS dest = wave-uniform base + lane*16 (m104/m108).
__device__ __forceinline__ void async_copy16(unsigned short* lds, const unsigned short* g) {
  __builtin_amdgcn_global_load_lds((const __attribute__((address_space(1))) void*)g,
                                   (__attribute__((address_space(3))) void*)lds,
                                   16, 0, 0);
}

// ---------------- fp32 -> bf16 conversion into workspace (unchanged from R3) ----------------
__global__ __launch_bounds__(256) void convert_bf16(const float* __restrict__ x,
                                                    const float* __restrict__ w,
                                                    unsigned short* __restrict__ xb,
                                                    unsigned short* __restrict__ wb) {
  const int half = gridDim.x >> 1;
  const float* src;
  unsigned short* dst;
  int b = blockIdx.x;
  if (b < half) { src = x; dst = xb; } else { src = w; dst = wb; b -= half; }
  const int64_t total  = (int64_t)MDIM * KDIM;
  const int64_t stride = (int64_t)half * 256 * 4;
  for (int64_t off = ((int64_t)b * 256 + threadIdx.x) * 4; off < total; off += stride) {
    float4 v = *(const float4*)(src + off);
    ushort4_t a = {f2bf(v.x), f2bf(v.y), f2bf(v.z), f2bf(v.w)};
    *(ushort4_t*)(dst + off) = a;
  }
}

// ---------------- 256x256 4-phase bf16 MFMA GEMM, read-one-phase-ahead ----------------
// v4: ds_reads for phase p+1 issue in phase p into a second register set;
// lgkmcnt(N_new) before MFMA drains only the PREVIOUS phase's reads (1 barrier +
// 1 MFMA cluster old -> ~zero stall). Reads/phase {4,8,0,12}, total 24/wave/tile.
//
// Register sets: avA=A0(t) [read P3(t-1)], avB=A1(t) [read P1(t)],
//   bvB=B1(t) [read P0(t)], bvE/bvO = B0 of even/odd tiles [read P3(t-1)]
//   (B0 double-buffered because P3 reads next B0 while MFMA'ing current B0).
// MFMA usage: P0:(avA,bv*) P1:(avA,bvB) P2:(avB,bvB) P3:(avB,bv*).
//
// Stage schedule (2 gload_lds per phase, all -> buf^1): P0:A0' P1:B0' P2:B1' P3:A1'.
// Wave-local vmcnt FIFO (steady, entering P0: [A1(t)]):
//   P0 +A0' ->4, vmcnt(2) confirms A1(t)   (read-issued P1(t))
//   P1 +B0' ->4, no wait
//   P2 +B1' ->6, vmcnt(2) confirms A0',B0' (read-issued P3(t))
//   P3 +A1' ->4, vmcnt(2) confirms B1'     (read-issued P0(t+1))
// Each vmcnt is BEFORE its phase's closing barrier -> cross-wave publication is
// correct (all waves confirm own loads, then barrier, then reads). Confirm lag
// 1.3-2.3 phases > HBM ~900cyc. Stage targets are >=3 barriers past the lgkm
// drain of their last reads (traced per-region).
__global__ __launch_bounds__(512, 2) void gemm_bf16(const unsigned short* __restrict__ A,
                                                    const unsigned short* __restrict__ B,
                                                    const float* __restrict__ bias,
                                                    float* __restrict__ C) {
  __shared__ __align__(16) unsigned short S[2][32768];  // 128 KiB
  const int tid = threadIdx.x;
  // bijective XCD rectangle swizzle: XCD c owns a 4(bm) x 8(bn) rectangle
  // -> per-K-tile per-XCD unique staging set = 12 panels (384 KB) -> L2-resident.
  const int id = blockIdx.x;
  const int xcd = id & 7, sblk = id >> 3;
  const int bm = (xcd >> 1) * 4 + (sblk >> 3);
  const int bn = (xcd & 1) * 8 + (sblk & 7);
  const int lane = tid & 63;
  const int wave = tid >> 6;                 // 8 waves
  const int quad = lane >> 4, r16 = lane & 15;
  const int wm = wave >> 2, wn = wave & 3;   // 2x4 wave grid; wave tile 128x64

  // staging constants (512 threads, 16B each; one issue = 8KB = 64 rows)
  const int rowa = tid >> 3;                 // 0..63
  const int slot = tid & 7;
  const int ch = slot ^ (rowa & 7);          // swizzled 16B chunk fetched
  const unsigned short* gA0 = A + (int64_t)(bm * 256 + rowa) * KDIM + ch * 8;
  const int growb = (rowa >> 5) * 64 + (rowa & 31);
  const unsigned short* gB0 = B + (int64_t)(bn * 256 + growb) * KDIM + ch * 8;

  // ds_read constants (shorts)
  const int offA = wm * 4096 + r16 * 64;
  const int offB = 16384 + wn * 2048 + r16 * 64;
  const int sw0 = (quad ^ (r16 & 7)) * 8;    // k-step h=0 chunk offset
  const int sw1 = sw0 ^ 32;                  // k-step h=1 (chunk ^ 4)

  floatx4 acc[8][4] = {};
  bf16x8 avA[4][2], avB[4][2];   // A0 / A1 fragment sets
  bf16x8 bvB[2][2];              // B1 fragments
  bf16x8 bvE[2][2], bvO[2][2];   // B0 fragments, even / odd tile parity

#define STAGE_A(BUF, MH, TT) do { \
    unsigned short* d_ = &S[BUF][(MH) * 8192 + tid * 8]; \
    const unsigned short* s_ = gA0 + (int64_t)((MH) * 64) * KDIM + (TT) * 64; \
    async_copy16(d_, s_); \
    async_copy16(d_ + 4096, s_ + (int64_t)128 * KDIM); \
  } while (0)

#define STAGE_B(BUF, NH, TT) do { \
    unsigned short* d_ = &S[BUF][16384 + (NH) * 8192 + tid * 8]; \
    const unsigned short* s_ = gB0 + (int64_t)((NH) * 32) * KDIM + (TT) * 64; \
    async_copy16(d_, s_); \
    async_copy16(d_ + 4096, s_ + (int64_t)128 * KDIM); \
  } while (0)

#define RD_A(DST, BUF, MH) do { \
    const unsigned short* Sb_ = &S[BUF][0]; \
    _Pragma("unroll") \
    for (int i = 0; i < 4; ++i) { \
      DST[i][0] = *(const bf16x8*)(Sb_ + (MH) * 8192 + offA + i * 1024 + sw0); \
      DST[i][1] = *(const bf16x8*)(Sb_ + (MH) * 8192 + offA + i * 1024 + sw1); \
    } \
  } while (0)

#define RD_B(DST, BUF, NH) do { \
    const unsigned short* Sb_ = &S[BUF][0]; \
    _Pragma("unroll") \
    for (int j = 0; j < 2; ++j) { \
      DST[j][0] = *(const bf16x8*)(Sb_ + (NH) * 8192 + offB + j * 1024 + sw0); \
      DST[j][1] = *(const bf16x8*)(Sb_ + (NH) * 8192 + offB + j * 1024 + sw1); \
    } \
  } while (0)

#define VM2 asm volatile("s_waitcnt vmcnt(2)" ::: "memory")
#define VMNONE (void)0

  // AV/BV: operand sets for THIS phase's MFMA (loaded in an earlier phase).
  // READ_STMT: ds_reads for the NEXT phase. LGKM_LIT: just-issued ds count.
#define PHASE(AV, BV, MOFF, NOFF, READ_STMT, STAGE_STMT, LGKM_LIT, WAIT_STMT) do { \
    READ_STMT; \
    STAGE_STMT; \
    asm volatile("s_waitcnt lgkmcnt(" LGKM_LIT ")" ::: "memory"); \
    __builtin_amdgcn_sched_barrier(0); \
    __builtin_amdgcn_s_setprio(1); \
    _Pragma("unroll") \
    for (int h = 0; h < 2; ++h) \
      _Pragma("unroll") \
      for (int i = 0; i < 4; ++i) \
        _Pragma("unroll") \
        for (int j = 0; j < 2; ++j) \
          acc[(MOFF) + i][(NOFF) + j] = __builtin_amdgcn_mfma_f32_16x16x32_bf16( \
              AV[i][h], BV[j][h], acc[(MOFF) + i][(NOFF) + j], 0, 0, 0); \
    __builtin_amdgcn_s_setprio(0); \
    WAIT_STMT; \
    __builtin_amdgcn_s_barrier(); \
    __builtin_amdgcn_sched_barrier(0); \
  } while (0)

  // prologue: stage tile0 (FIFO: A0,B0,B1,A1); vmcnt(2) confirms A0,B0,B1
  // (leaves A1(0) in flight = steady-state entry shape); read A0,B0 for P0(0).
  STAGE_A(0, 0, 0);
  STAGE_B(0, 0, 0);
  STAGE_B(0, 1, 0);
  STAGE_A(0, 1, 0);
  asm volatile("s_waitcnt vmcnt(2)" ::: "memory");
  __builtin_amdgcn_s_barrier();
  RD_A(avA, 0, 0);
  RD_B(bvE, 0, 0);

  for (int it = 0; it < NT / 2; ++it) {
    const int u = it * 2;
    const int t1 = u + 1;
    const int t2 = (u + 2) & (NT - 1);   // wrapped at tail: staged/read but never used
    // tile u (buf0, B0 in bvE; stage tile t1 -> buf1)
    PHASE(avA, bvE, 0, 0, RD_B(bvB, 0, 1),                    STAGE_A(1, 0, t1), "4",  VM2);
    PHASE(avA, bvB, 0, 2, RD_A(avB, 0, 1),                    STAGE_B(1, 0, t1), "8",  VMNONE);
    PHASE(avB, bvB, 4, 2, (void)0,                            STAGE_B(1, 1, t1), "0",  VM2);
    PHASE(avB, bvE, 4, 0, { RD_A(avA, 1, 0); RD_B(bvO, 1, 0); }, STAGE_A(1, 1, t1), "12", VM2);
    // tile t1 (buf1, B0 in bvO; stage tile t2 -> buf0)
    PHASE(avA, bvO, 0, 0, RD_B(bvB, 1, 1),                    STAGE_A(0, 0, t2), "4",  VM2);
    PHASE(avA, bvB, 0, 2, RD_A(avB, 1, 1),                    STAGE_B(0, 0, t2), "8",  VMNONE);
    PHASE(avB, bvB, 4, 2, (void)0,                            STAGE_B(0, 1, t2), "0",  VM2);
    PHASE(avB, bvO, 4, 0, { RD_A(avA, 0, 0); RD_B(bvE, 0, 0); }, STAGE_A(0, 1, t2), "12", VM2);
  }
  asm volatile("s_waitcnt vmcnt(0)" ::: "memory");

#undef PHASE
#undef VM2
#undef VMNONE
#undef RD_A
#undef RD_B
#undef STAGE_A
#undef STAGE_B

  // epilogue: C/D layout col = lane&15, row = quad*4 + r (m89-verified)
  const int col0 = bn * 256 + wn * 64 + r16;
  const int row0 = bm * 256 + wm * 128 + quad * 4;
#pragma unroll
  for (int nj = 0; nj < 4; ++nj) {
    const float bvv = bias[col0 + nj * 16];
#pragma unroll
    for (int mi = 0; mi < 8; ++mi) {
      float* cp = C + (int64_t)(row0 + mi * 16) * NDIM + col0 + nj * 16;
#pragma unroll
      for (int r = 0; r < 4; ++r)
        cp[(int64_t)r * NDIM] = acc[mi][nj][r] + bvv;
    }
  }
}

// ---------------- fallback: fp32 inputs, convert in staging (no workspace) ----------------
#define BM 128
#define BN 128
#define FBK 32
__global__ __launch_bounds__(256) void gemm_f32in(const float* __restrict__ A,
                                                  const float* __restrict__ W,
                                                  const float* __restrict__ bias,
                                                  float* __restrict__ C) {
  __shared__ __align__(16) unsigned short As[BM * FBK];
  __shared__ __align__(16) unsigned short Bs[BN * FBK];
  const int tid = threadIdx.x;
  const int bm = blockIdx.y, bn = blockIdx.x;
  const int lane = tid & 63, wave = tid >> 6;
  const int quad = lane >> 4, r16 = lane & 15;
  const int wm = (wave >> 1) * 64, wn = (wave & 1) * 64;

  const int srow = tid >> 1;
  const int scol = (tid & 1) * 16;
  const float* ag = A + (int64_t)(bm * BM + srow) * KDIM + scol;
  const float* bg = W + (int64_t)(bn * BN + srow) * KDIM + scol;
  unsigned short* al = As + srow * FBK + scol;
  unsigned short* bl = Bs + srow * FBK + scol;

  floatx4 acc[4][4] = {};
  for (int k0 = 0; k0 < KDIM; k0 += FBK) {
    float4 a0 = *(const float4*)(ag + k0);
    float4 a1 = *(const float4*)(ag + k0 + 4);
    float4 a2 = *(const float4*)(ag + k0 + 8);
    float4 a3 = *(const float4*)(ag + k0 + 12);
    float4 b0 = *(const float4*)(bg + k0);
    float4 b1 = *(const float4*)(bg + k0 + 4);
    float4 b2 = *(const float4*)(bg + k0 + 8);
    float4 b3 = *(const float4*)(bg + k0 + 12);
    ushort8_t pa0 = {f2bf(a0.x), f2bf(a0.y), f2bf(a0.z), f2bf(a0.w),
                     f2bf(a1.x), f2bf(a1.y), f2bf(a1.z), f2bf(a1.w)};
    ushort8_t pa1 = {f2bf(a2.x), f2bf(a2.y), f2bf(a2.z), f2bf(a2.w),
                     f2bf(a3.x), f2bf(a3.y), f2bf(a3.z), f2bf(a3.w)};
    ushort8_t pb0 = {f2bf(b0.x), f2bf(b0.y), f2bf(b0.z), f2bf(b0.w),
                     f2bf(b1.x), f2bf(b1.y), f2bf(b1.z), f2bf(b1.w)};
    ushort8_t pb1 = {f2bf(b2.x), f2bf(b2.y), f2bf(b2.z), f2bf(b2.w),
                     f2bf(b3.x), f2bf(b3.y), f2bf(b3.z), f2bf(b3.w)};
    *(ushort8_t*)al = pa0;
    *(ushort8_t*)(al + 8) = pa1;
    *(ushort8_t*)bl = pb0;
    *(ushort8_t*)(bl + 8) = pb1;
    __syncthreads();

    bf16x8 a[4], b[4];
#pragma unroll
    for (int i = 0; i < 4; ++i)
      a[i] = *(const bf16x8*)(As + (wm + i * 16 + r16) * FBK + quad * 8);
#pragma unroll
    for (int i = 0; i < 4; ++i)
      b[i] = *(const bf16x8*)(Bs + (wn + i * 16 + r16) * FBK + quad * 8);
#pragma unroll
    for (int i = 0; i < 4; ++i)
#pragma unroll
      for (int j = 0; j < 4; ++j)
        acc[i][j] = __builtin_amdgcn_mfma_f32_16x16x32_bf16(a[i], b[j], acc[i][j], 0, 0, 0);
    __syncthreads();
  }

  const int col0 = bn * BN + wn + r16;
  const int row0 = bm * BM + wm + quad * 4;
#pragma unroll
  for (int j = 0; j < 4; ++j) {
    const float bv = bias[col0 + j * 16];
#pragma unroll
    for (int i = 0; i < 4; ++i) {
      float* cp = C + (int64_t)(row0 + i * 16) * NDIM + col0 + j * 16;
#pragma unroll
      for (int r = 0; r < 4; ++r)
        cp[(int64_t)r * NDIM] = acc[i][j][r] + bv;
    }
  }
}

extern "C" void kernel_launch(void* const* d_in, const int* in_sizes, int n_in,
                              void* d_out, int out_size, void* d_ws, size_t ws_size,
                              hipStream_t stream) {
  const float* x    = (const float*)d_in[0];   // [4096, 4096]
  const float* w    = (const float*)d_in[1];   // [4096, 4096]
  const float* bias = (const float*)d_in[2];   // [4096]
  float* out = (float*)d_out;

  const size_t need = (size_t)2 * MDIM * KDIM * sizeof(unsigned short);  // 64 MB
  if (ws_size >= need) {
    unsigned short* xb = (unsigned short*)d_ws;
    unsigned short* wb = xb + (size_t)MDIM * KDIM;
    convert_bf16<<<4096, 256, 0, stream>>>(x, w, xb, wb);
    gemm_bf16<<<256, 512, 0, stream>>>(xb, wb, bias, out);  // 1-D grid, XCD-swizzled in-kernel
  } else {
    dim3 grid(NDIM / BN, MDIM / BM);
    gemm_f32in<<<grid, 256, 0, stream>>>(x, w, bias, out);
  }
}